// Round 1
// baseline (868.222 us; speedup 1.0000x reference)
//
#include <hip/hip_runtime.h>
#include <math.h>

// Problem constants (x: [2,16,2048,2048] fp32, W: [2048,2048], b: [2048])
constexpr int S      = 2048;
constexpr int BH     = 32;            // 2*16 heads
constexpr int NROWS  = BH * S;        // 65536 rows of length S
constexpr int KS     = 16;            // split-K factor for the small GEMM
constexpr int KR     = S / KS;        // 128 K per split

typedef float v4f __attribute__((ext_vector_type(4)));

// ws layout:
//   [0,                 NROWS*4)        : G    float[NROWS]   row maxes (G[bh*S+s])
//   [NROWS*4,           2*NROWS*4)      : IDX  int[NROWS]     argmax col per row
//   [2*NROWS*4,         +KS*NROWS*4)    : part float[KS][BH][S] split-K partials
// total = 256KB + 256KB + 4MB = 4.5 MB

// ---------------------------------------------------------------------------
// Kernel A: fused copy x->out + per-row (max, argmax). One 64-lane wave per row.
// All 8 nontemporal loads issued first (8x16B/lane in flight), then 8 NT
// stores, then the argmax compare chain runs purely on registers. NT hints
// keep the 1 GB dead stream from write-allocating L2/LLC.
// ---------------------------------------------------------------------------
__global__ __launch_bounds__(256) void rowmax_copy_kernel(
    const float* __restrict__ x, float* __restrict__ out,
    float* __restrict__ G, int* __restrict__ IDX)
{
    const int wave = threadIdx.x >> 6;
    const int lane = threadIdx.x & 63;
    const int row  = blockIdx.x * 4 + wave;

    const v4f* xr   = (const v4f*)(x   + (size_t)row * S);
    v4f*       outr = (v4f*)      (out + (size_t)row * S);

    v4f v[8];
    #pragma unroll
    for (int c = 0; c < 8; ++c)
        v[c] = __builtin_nontemporal_load(xr + c * 64 + lane);

    #pragma unroll
    for (int c = 0; c < 8; ++c)
        __builtin_nontemporal_store(v[c], outr + c * 64 + lane);

    float best = -INFINITY;
    int   bidx = 0;
    #pragma unroll
    for (int c = 0; c < 8; ++c) {
        const int base = (c * 64 + lane) * 4;
        // strict '>' with increasing index order => first occurrence per lane
        if (v[c].x > best) { best = v[c].x; bidx = base;     }
        if (v[c].y > best) { best = v[c].y; bidx = base + 1; }
        if (v[c].z > best) { best = v[c].z; bidx = base + 2; }
        if (v[c].w > best) { best = v[c].w; bidx = base + 3; }
    }
    // wave (64-lane) reduction; tie -> smaller index (jnp.argmax first-occurrence)
    #pragma unroll
    for (int off = 32; off > 0; off >>= 1) {
        float ov = __shfl_down(best, off, 64);
        int   oi = __shfl_down(bidx, off, 64);
        if (ov > best || (ov == best && oi < bidx)) { best = ov; bidx = oi; }
    }
    if (lane == 0) {
        G[row]   = best;
        IDX[row] = bidx;
    }
}

// ---------------------------------------------------------------------------
// Kernel B: split-K GEMM  Y[bh][t] = sum_s G[bh][s] * W[t][s]
// Grid (S/128, KS) = 256 blocks (1/CU). Each thread owns one t and 16 bh.
// G is read at WAVE-UNIFORM addresses -> compiler emits s_load (scalar pipe),
// no LDS, no LDS broadcast cost. W is read exactly once across the grid.
// ---------------------------------------------------------------------------
__global__ __launch_bounds__(256) void gemm_part_kernel(
    const float* __restrict__ G, const float* __restrict__ W,
    float* __restrict__ part)
{
    const int tid = threadIdx.x;
    const int t   = blockIdx.x * 128 + (tid & 127);
    const int bhb = (tid >> 7) * 16;          // 0 or 16 (wave-uniform)
    const int k0  = blockIdx.y * KR;

    float acc[16];
    #pragma unroll
    for (int i = 0; i < 16; ++i) acc[i] = 0.0f;

    const v4f*   wr = (const v4f*)(W + (size_t)t * S + k0);
    const float* gp = G + bhb * S + k0;       // wave-uniform base

    #pragma unroll 2
    for (int k = 0; k < KR; k += 4) {
        const v4f w = wr[k >> 2];
        #pragma unroll
        for (int i = 0; i < 16; ++i) {
            const float* g = gp + i * S + k;  // wave-uniform -> s_load_dwordx4
            acc[i] += w.x * g[0] + w.y * g[1] + w.z * g[2] + w.w * g[3];
        }
    }

    #pragma unroll
    for (int i = 0; i < 16; ++i) {
        // part[ks][bh][t] — coalesced (t contiguous across lanes)
        part[(size_t)(blockIdx.y * BH + bhb + i) * S + t] = acc[i];
    }
}

// ---------------------------------------------------------------------------
// Kernel C: reduce split-K partials + bias, exact-erf GELU, scatter into out.
// ---------------------------------------------------------------------------
__global__ __launch_bounds__(256) void finish_kernel(
    const float* __restrict__ part, const float* __restrict__ bias,
    const int* __restrict__ IDX, float* __restrict__ out)
{
    const int o  = blockIdx.x * 256 + threadIdx.x;  // 0..NROWS-1 == (bh, t)
    const int t  = o & (S - 1);
    const int bh = o >> 11;

    float s = bias[t];
    #pragma unroll
    for (int ks = 0; ks < KS; ++ks)
        s += part[(size_t)(ks * BH + bh) * S + t];

    // exact GELU: 0.5*x*(1+erf(x/sqrt(2)))
    const float y = 0.5f * s * (1.0f + erff(s * 0.70710678118654752440f));

    const int idx = IDX[o];
    out[(size_t)o * S + idx] = y;
}

extern "C" void kernel_launch(void* const* d_in, const int* in_sizes, int n_in,
                              void* d_out, int out_size, void* d_ws, size_t ws_size,
                              hipStream_t stream) {
    const float* x = (const float*)d_in[0];   // [2,16,2048,2048]
    const float* W = (const float*)d_in[1];   // [2048,2048]
    const float* b = (const float*)d_in[2];   // [2048]
    float* out = (float*)d_out;

    float* G    = (float*)d_ws;
    int*   IDX  = (int*)  ((char*)d_ws + (size_t)NROWS * 4);
    float* part = (float*)((char*)d_ws + (size_t)2 * NROWS * 4);

    // A: copy + row max/argmax (memory-bound, ~1 GB HBM traffic)
    rowmax_copy_kernel<<<NROWS / 4, 256, 0, stream>>>(x, out, G, IDX);

    // B: split-K GEMM partials (scalar-pipe G reads, 1 block/CU)
    dim3 gridB(S / 128, KS);
    gemm_part_kernel<<<gridB, 256, 0, stream>>>(G, W, part);

    // C: reduce + GELU + scatter
    finish_kernel<<<NROWS / 256, 256, 0, stream>>>(part, b, IDX, out);
}

// Round 2
// 847.727 us; speedup vs baseline: 1.0242x; 1.0242x over previous
//
#include <hip/hip_runtime.h>
#include <math.h>

// Problem constants (x: [2,16,2048,2048] fp32, W: [2048,2048], b: [2048])
constexpr int S      = 2048;
constexpr int BH     = 32;            // 2*16 heads
constexpr int NROWS  = BH * S;        // 65536 rows of length S

typedef float v4f __attribute__((ext_vector_type(4)));

// ws layout:
//   [0,           NROWS*4)    : G    float[NROWS]   row maxes (G[bh*S+s])
//   [NROWS*4,   2*NROWS*4)    : IDX  int[NROWS]     argmax col per row
// total = 512 KB

// ---------------------------------------------------------------------------
// Kernel A: fused copy x->out + per-row (max, argmax). One 64-lane wave per row.
// All 8 nontemporal loads issued first (8x16B/lane in flight), then 8 NT
// stores, then the argmax compare chain runs purely on registers. NT hints
// keep the 1 GB dead stream from write-allocating L2/LLC.
// At the mandatory-traffic floor: 0.5 GB read + 0.5 GB write ≈ 175 µs @6.3TB/s.
// ---------------------------------------------------------------------------
__global__ __launch_bounds__(256) void rowmax_copy_kernel(
    const float* __restrict__ x, float* __restrict__ out,
    float* __restrict__ G, int* __restrict__ IDX)
{
    const int wave = threadIdx.x >> 6;
    const int lane = threadIdx.x & 63;
    const int row  = blockIdx.x * 4 + wave;

    const v4f* xr   = (const v4f*)(x   + (size_t)row * S);
    v4f*       outr = (v4f*)      (out + (size_t)row * S);

    v4f v[8];
    #pragma unroll
    for (int c = 0; c < 8; ++c)
        v[c] = __builtin_nontemporal_load(xr + c * 64 + lane);

    #pragma unroll
    for (int c = 0; c < 8; ++c)
        __builtin_nontemporal_store(v[c], outr + c * 64 + lane);

    float best = -INFINITY;
    int   bidx = 0;
    #pragma unroll
    for (int c = 0; c < 8; ++c) {
        const int base = (c * 64 + lane) * 4;
        // strict '>' with increasing index order => first occurrence per lane
        if (v[c].x > best) { best = v[c].x; bidx = base;     }
        if (v[c].y > best) { best = v[c].y; bidx = base + 1; }
        if (v[c].z > best) { best = v[c].z; bidx = base + 2; }
        if (v[c].w > best) { best = v[c].w; bidx = base + 3; }
    }
    // wave (64-lane) reduction; tie -> smaller index (jnp.argmax first-occurrence)
    #pragma unroll
    for (int off = 32; off > 0; off >>= 1) {
        float ov = __shfl_down(best, off, 64);
        int   oi = __shfl_down(bidx, off, 64);
        if (ov > best || (ov == best && oi < bidx)) { best = ov; bidx = oi; }
    }
    if (lane == 0) {
        G[row]   = best;
        IDX[row] = bidx;
    }
}

// ---------------------------------------------------------------------------
// Kernel BC: fused GEMM + bias + exact-erf GELU + scatter.
//   y[bh][t] = gelu( sum_k G[bh][k] * W[t][k] + b[t] );  out[bh, t, IDX[bh,t]] = y
// Grid (S/16, 2) = 256 blocks (1/CU), 512 threads (8 waves).
// Each block: one bh-half (16 rows of G, 128 KB staged in LDS — m201 precedent
// for 128 KiB static LDS on gfx950). Each wave owns two t's; lanes span k, so
// W loads are fully coalesced (16 B/lane consecutive) and each ds_read_b128 of
// G is reused for both t accumulators. Butterfly-reduce, then lanes 0..15
// finish one bh each. Replaces split-K part buffer (8 MB traffic) + kernel C.
// ---------------------------------------------------------------------------
__global__ __launch_bounds__(512) void gemm_gelu_scatter_kernel(
    const float* __restrict__ G, const float* __restrict__ W,
    const float* __restrict__ bias, const int* __restrict__ IDX,
    float* __restrict__ out)
{
    __shared__ float g_lds[16 * S];          // 128 KB
    const int tid  = threadIdx.x;
    const int lane = tid & 63;
    const int wv   = tid >> 6;               // 0..7
    const int bh0  = blockIdx.y * 16;
    const int t0   = blockIdx.x * 16;

    // Stage 16 G rows (32768 floats) with 512 threads: 16 float4 each, coalesced.
    {
        const v4f* gsrc = (const v4f*)(G + (size_t)bh0 * S);
        v4f* gdst = (v4f*)g_lds;
        #pragma unroll
        for (int r = 0; r < 16; ++r)
            gdst[tid + r * 512] = gsrc[tid + r * 512];
    }
    __syncthreads();

    const int tA = t0 + wv;                  // wave's two output positions
    const int tB = t0 + 8 + wv;

    float accA[16], accB[16];
    #pragma unroll
    for (int i = 0; i < 16; ++i) { accA[i] = 0.0f; accB[i] = 0.0f; }

    const v4f* wrA = (const v4f*)(W + (size_t)tA * S);
    const v4f* wrB = (const v4f*)(W + (size_t)tB * S);

    #pragma unroll
    for (int c = 0; c < 8; ++c) {
        const int kv = c * 64 + lane;        // float4 index within the row
        const v4f wa = wrA[kv];
        const v4f wb = wrB[kv];
        #pragma unroll
        for (int i = 0; i < 16; ++i) {
            const v4f g = *(const v4f*)&g_lds[i * S + kv * 4];  // conflict-free
            accA[i] += wa.x * g.x + wa.y * g.y + wa.z * g.z + wa.w * g.w;
            accB[i] += wb.x * g.x + wb.y * g.y + wb.z * g.z + wb.w * g.w;
        }
    }

    // 64-lane butterfly reduce; every lane ends with the full sums.
    #pragma unroll
    for (int i = 0; i < 16; ++i) {
        #pragma unroll
        for (int off = 32; off > 0; off >>= 1) {
            accA[i] += __shfl_xor(accA[i], off, 64);
            accB[i] += __shfl_xor(accB[i], off, 64);
        }
    }

    // lane i (<16) takes bh = bh0 + i; select via short cndmask chain
    float yA = accA[0], yB = accB[0];
    #pragma unroll
    for (int i = 1; i < 16; ++i) {
        if (lane == i) { yA = accA[i]; yB = accB[i]; }
    }

    if (lane < 16) {
        const int bh = bh0 + lane;
        float sA = yA + bias[tA];
        float sB = yB + bias[tB];
        // exact GELU: 0.5*x*(1+erf(x/sqrt(2)))
        sA = 0.5f * sA * (1.0f + erff(sA * 0.70710678118654752440f));
        sB = 0.5f * sB * (1.0f + erff(sB * 0.70710678118654752440f));
        const size_t rA = (size_t)bh * S + tA;
        const size_t rB = (size_t)bh * S + tB;
        out[rA * S + IDX[rA]] = sA;
        out[rB * S + IDX[rB]] = sB;
    }
}

extern "C" void kernel_launch(void* const* d_in, const int* in_sizes, int n_in,
                              void* d_out, int out_size, void* d_ws, size_t ws_size,
                              hipStream_t stream) {
    const float* x = (const float*)d_in[0];   // [2,16,2048,2048]
    const float* W = (const float*)d_in[1];   // [2048,2048]
    const float* b = (const float*)d_in[2];   // [2048]
    float* out = (float*)d_out;

    float* G   = (float*)d_ws;
    int*   IDX = (int*)  ((char*)d_ws + (size_t)NROWS * 4);

    // A: copy + row max/argmax (memory-bound, ~1 GB HBM traffic)
    rowmax_copy_kernel<<<NROWS / 4, 256, 0, stream>>>(x, out, G, IDX);

    // BC: fused GEMM + GELU + scatter (W read coalesced, 2x total = 32 MB)
    dim3 gridBC(S / 16, 2);
    gemm_gelu_scatter_kernel<<<gridBC, 512, 0, stream>>>(G, W, b, IDX, out);
}